// Round 1
// baseline (64.089 us; speedup 1.0000x reference)
//
#include <hip/hip_runtime.h>

// FLF quantizer: nearest code in {-1,+1}^16 is elementwise sign(z), index is
// the MSB-first bit pattern of (z > 0). No 65536-wide distance matrix needed.
//
// Layout: [8,256,128] x -> 2048 tokens. One block = 16 tokens, 256 threads.
// Thread (t = tid>>4, e = tid&15):
//   phase 1: z[t][e] = b_in[e] + dot(x[t], W_in[:,e])  (float4 LDS reads)
//   ballot  : 16-lane group shares sign bits; idx = brev(field)>>16
//   phase 2: same thread computes 8 output floats of token t.

#define DIMX 128
#define DCODE 16
#define TOK_PER_BLK 16
#define LDS_PITCH 132   // 128 + 4: keeps 16B alignment, breaks pow2 bank stride

__global__ __launch_bounds__(256)
void flfq_fused_kernel(const float* __restrict__ x,     // [n_tok,128]
                       const float* __restrict__ Win,   // [128,16]
                       const float* __restrict__ bin,   // [16]
                       const float* __restrict__ Wout,  // [16,128]
                       const float* __restrict__ bout,  // [128]
                       float* __restrict__ out,         // [n_tok*128] ++ [n_tok]
                       int n_tok) {
  __shared__ float xs[TOK_PER_BLK * LDS_PITCH];
  __shared__ float wt[DCODE * LDS_PITCH];   // W_in transposed: wt[e][d]
  __shared__ float wo[DCODE * LDS_PITCH];   // W_out as-is:    wo[e][d]

  const int tid = threadIdx.x;
  const int tok0 = blockIdx.x * TOK_PER_BLK;
  const long long total_x = (long long)n_tok * DIMX;

  // ---- stage x tile: 16*128 floats, 2 float4 per thread, coalesced ----
  {
    const float* xg = x + (long long)tok0 * DIMX;
#pragma unroll
    for (int k = 0; k < 2; ++k) {
      int j = (tid + k * 256) * 4;           // 0..2044 step 4
      int row = j >> 7, col = j & 127;
      float4 v = make_float4(0.f, 0.f, 0.f, 0.f);
      if ((long long)tok0 * DIMX + j + 3 < total_x)
        v = *reinterpret_cast<const float4*>(xg + j);
      *reinterpret_cast<float4*>(&xs[row * LDS_PITCH + col]) = v;
    }
  }
  // ---- stage W_in transposed (coalesced read, scattered LDS write) ----
  for (int j = tid; j < DIMX * DCODE; j += 256) {
    int d = j >> 4, e = j & 15;
    wt[e * LDS_PITCH + d] = Win[j];
  }
  // ---- stage W_out straight copy, float4 ----
#pragma unroll
  for (int k = 0; k < 2; ++k) {
    int j = (tid + k * 256) * 4;
    int row = j >> 7, col = j & 127;
    *reinterpret_cast<float4*>(&wo[row * LDS_PITCH + col]) =
        *reinterpret_cast<const float4*>(Wout + j);
  }
  __syncthreads();

  const int t = tid >> 4;    // token slot within block
  const int e = tid & 15;    // code dim for phase 1 / d-group for phase 2
  const int gtok = tok0 + t;

  // ---- phase 1: z = b_in[e] + dot128(xs[t], wt[e]) ----
  float a0 = 0.f, a1 = 0.f, a2 = 0.f, a3 = 0.f;
  const float* xrow = &xs[t * LDS_PITCH];
  const float* wrow = &wt[e * LDS_PITCH];
#pragma unroll
  for (int d = 0; d < DIMX; d += 4) {
    float4 xv = *reinterpret_cast<const float4*>(xrow + d);
    float4 wv = *reinterpret_cast<const float4*>(wrow + d);
    a0 = fmaf(xv.x, wv.x, a0);
    a1 = fmaf(xv.y, wv.y, a1);
    a2 = fmaf(xv.z, wv.z, a2);
    a3 = fmaf(xv.w, wv.w, a3);
  }
  float z = bin[e] + ((a0 + a2) + (a1 + a3));

  // ---- pack sign bits via wave ballot (16-lane groups, 4 tokens/wave) ----
  // bit e set <=> z_e > 0 (tie z==0 -> -1 -> bit 0, matching argmin tiebreak)
  unsigned long long bal = __ballot(z > 0.0f);
  const int s = (tid & 63) >> 4;  // token slot within the wave
  unsigned int field = (unsigned int)((bal >> (s * 16)) & 0xFFFFull);
  unsigned int idx = __brev(field) >> 16;  // bit e (lane order) -> bit 15-e

  if (e == 0 && gtok < n_tok)
    out[(long long)n_tok * DIMX + gtok] = (float)idx;  // index as fp32 value

  // ---- phase 2: out[t][d] = b_out[d] + sum_e sign_e * W_out[e][d] ----
  // thread covers d in [4e,4e+4) and [64+4e,64+4e+4): 16 lanes -> 256B/store
  const int d0 = e * 4;
  float4 s0 = *reinterpret_cast<const float4*>(bout + d0);
  float4 s1 = *reinterpret_cast<const float4*>(bout + 64 + d0);
#pragma unroll
  for (int ee = 0; ee < DCODE; ++ee) {
    float sgn = ((idx >> (15 - ee)) & 1u) ? 1.0f : -1.0f;
    float4 w0 = *reinterpret_cast<const float4*>(&wo[ee * LDS_PITCH + d0]);
    float4 w1 = *reinterpret_cast<const float4*>(&wo[ee * LDS_PITCH + 64 + d0]);
    s0.x = fmaf(sgn, w0.x, s0.x);
    s0.y = fmaf(sgn, w0.y, s0.y);
    s0.z = fmaf(sgn, w0.z, s0.z);
    s0.w = fmaf(sgn, w0.w, s0.w);
    s1.x = fmaf(sgn, w1.x, s1.x);
    s1.y = fmaf(sgn, w1.y, s1.y);
    s1.z = fmaf(sgn, w1.z, s1.z);
    s1.w = fmaf(sgn, w1.w, s1.w);
  }
  if (gtok < n_tok) {
    float* orow = out + (long long)gtok * DIMX;
    *reinterpret_cast<float4*>(orow + d0) = s0;
    *reinterpret_cast<float4*>(orow + 64 + d0) = s1;
  }
}

extern "C" void kernel_launch(void* const* d_in, const int* in_sizes, int n_in,
                              void* d_out, int out_size, void* d_ws, size_t ws_size,
                              hipStream_t stream) {
  const float* x    = (const float*)d_in[0];  // [8,256,128]
  const float* Win  = (const float*)d_in[1];  // [128,16]
  const float* bin  = (const float*)d_in[2];  // [16]
  const float* Wout = (const float*)d_in[3];  // [16,128]
  const float* bout = (const float*)d_in[4];  // [128]
  float* out = (float*)d_out;                 // 262144 out floats ++ 2048 idx

  const int n_tok = in_sizes[0] / DIMX;       // 2048
  const int grid = (n_tok + TOK_PER_BLK - 1) / TOK_PER_BLK;  // 128
  flfq_fused_kernel<<<grid, 256, 0, stream>>>(x, Win, bin, Wout, bout, out, n_tok);
}

// Round 2
// 61.899 us; speedup vs baseline: 1.0354x; 1.0354x over previous
//
#include <hip/hip_runtime.h>

// FLF quantizer: nearest code in {-1,+1}^16 is elementwise sign(z); index is
// the MSB-first bit pattern of (z > 0), ties (z==0) -> -1 (bit 0), matching
// argmin's lowest-index tiebreak. No 65536-wide distance matrix.
//
// R2: 256 blocks x 128 threads, 8 tokens/block -> one block per CU (256 CUs),
// halving the per-block LDS-read critical path vs R1's 128-block launch.
//
// Thread (t = tid>>4 in [0,8), e = tid&15):
//   phase 1: z[t][e] = b_in[e] + dot128(x[t], W_in[:,e])   (float4 LDS reads)
//   ballot : 16-lane groups share sign bits; idx = brev(field)>>16
//   phase 2: same thread accumulates 8 output floats of token t (2x float4).

#define DIMX 128
#define DCODE 16
#define TOK_PER_BLK 8
#define BLOCK 128
#define LDS_PITCH 132   // 128 + 4: keeps 16B alignment, breaks pow2 bank stride

__global__ __launch_bounds__(BLOCK)
void flfq_fused_kernel(const float* __restrict__ x,     // [n_tok,128]
                       const float* __restrict__ Win,   // [128,16]
                       const float* __restrict__ bin,   // [16]
                       const float* __restrict__ Wout,  // [16,128]
                       const float* __restrict__ bout,  // [128]
                       float* __restrict__ out,         // [n_tok*128] ++ [n_tok]
                       int n_tok) {
  __shared__ float xs[TOK_PER_BLK * LDS_PITCH];
  __shared__ float wt[DCODE * LDS_PITCH];   // W_in transposed: wt[e][d]
  __shared__ float wo[DCODE * LDS_PITCH];   // W_out as-is:    wo[e][d]

  const int tid = threadIdx.x;
  const int tok0 = blockIdx.x * TOK_PER_BLK;

  // ---- stage x tile: 8*128 floats = 256 float4; 2 per thread, coalesced ----
  {
    const float* xg = x + (long long)tok0 * DIMX;
#pragma unroll
    for (int k = 0; k < 2; ++k) {
      int j = (tid + k * BLOCK) * 4;         // 0..1020 step 4 (floats)
      int row = j >> 7, col = j & 127;
      float4 v = *reinterpret_cast<const float4*>(xg + j);
      *reinterpret_cast<float4*>(&xs[row * LDS_PITCH + col]) = v;
    }
  }
  // ---- stage W_in transposed: float4 spans 4 e's of one d ----
#pragma unroll
  for (int k = 0; k < 4; ++k) {
    int q = tid + k * BLOCK;                 // 0..511 (float4 index)
    int d = q >> 2, e0 = (q & 3) * 4;
    float4 v = *reinterpret_cast<const float4*>(Win + q * 4);
    wt[(e0 + 0) * LDS_PITCH + d] = v.x;
    wt[(e0 + 1) * LDS_PITCH + d] = v.y;
    wt[(e0 + 2) * LDS_PITCH + d] = v.z;
    wt[(e0 + 3) * LDS_PITCH + d] = v.w;
  }
  // ---- stage W_out straight copy, float4 ----
#pragma unroll
  for (int k = 0; k < 4; ++k) {
    int j = (tid + k * BLOCK) * 4;           // 0..2044 step 4
    int row = j >> 7, col = j & 127;
    *reinterpret_cast<float4*>(&wo[row * LDS_PITCH + col]) =
        *reinterpret_cast<const float4*>(Wout + j);
  }
  __syncthreads();

  const int t = tid >> 4;    // token slot within block (0..7)
  const int e = tid & 15;    // code dim for phase 1 / d-group for phase 2
  const int gtok = tok0 + t;

  // ---- phase 1: z = b_in[e] + dot128(xs[t], wt[e]) ----
  float a0 = 0.f, a1 = 0.f, a2 = 0.f, a3 = 0.f;
  const float* xrow = &xs[t * LDS_PITCH];
  const float* wrow = &wt[e * LDS_PITCH];
#pragma unroll
  for (int d = 0; d < DIMX; d += 4) {
    float4 xv = *reinterpret_cast<const float4*>(xrow + d);
    float4 wv = *reinterpret_cast<const float4*>(wrow + d);
    a0 = fmaf(xv.x, wv.x, a0);
    a1 = fmaf(xv.y, wv.y, a1);
    a2 = fmaf(xv.z, wv.z, a2);
    a3 = fmaf(xv.w, wv.w, a3);
  }
  float z = bin[e] + ((a0 + a2) + (a1 + a3));

  // ---- pack sign bits via wave ballot (16-lane groups, 4 tokens/wave) ----
  unsigned long long bal = __ballot(z > 0.0f);
  const int s = (tid & 63) >> 4;  // token slot within the wave
  unsigned int field = (unsigned int)((bal >> (s * 16)) & 0xFFFFull);
  unsigned int idx = __brev(field) >> 16;  // lane-order bit e -> idx bit 15-e

  // ---- phase 2: out[t][d] = b_out[d] + sum_e sign_e * W_out[e][d] ----
  // thread covers d in [4e,4e+4) and [64+4e,64+4e+4): 16 lanes = 256B/store
  const int d0 = e * 4;
  float4 s0 = *reinterpret_cast<const float4*>(bout + d0);
  float4 s1 = *reinterpret_cast<const float4*>(bout + 64 + d0);
#pragma unroll
  for (int ee = 0; ee < DCODE; ++ee) {
    float sgn = ((idx >> (15 - ee)) & 1u) ? 1.0f : -1.0f;
    float4 w0 = *reinterpret_cast<const float4*>(&wo[ee * LDS_PITCH + d0]);
    float4 w1 = *reinterpret_cast<const float4*>(&wo[ee * LDS_PITCH + 64 + d0]);
    s0.x = fmaf(sgn, w0.x, s0.x);
    s0.y = fmaf(sgn, w0.y, s0.y);
    s0.z = fmaf(sgn, w0.z, s0.z);
    s0.w = fmaf(sgn, w0.w, s0.w);
    s1.x = fmaf(sgn, w1.x, s1.x);
    s1.y = fmaf(sgn, w1.y, s1.y);
    s1.z = fmaf(sgn, w1.z, s1.z);
    s1.w = fmaf(sgn, w1.w, s1.w);
  }
  if (gtok < n_tok) {
    float* orow = out + (long long)gtok * DIMX;
    *reinterpret_cast<float4*>(orow + d0) = s0;
    *reinterpret_cast<float4*>(orow + 64 + d0) = s1;
    if (e == 0)
      out[(long long)n_tok * DIMX + gtok] = (float)idx;  // index as fp32 value
  }
}

extern "C" void kernel_launch(void* const* d_in, const int* in_sizes, int n_in,
                              void* d_out, int out_size, void* d_ws, size_t ws_size,
                              hipStream_t stream) {
  const float* x    = (const float*)d_in[0];  // [8,256,128]
  const float* Win  = (const float*)d_in[1];  // [128,16]
  const float* bin  = (const float*)d_in[2];  // [16]
  const float* Wout = (const float*)d_in[3];  // [16,128]
  const float* bout = (const float*)d_in[4];  // [128]
  float* out = (float*)d_out;                 // 262144 out floats ++ 2048 idx

  const int n_tok = in_sizes[0] / DIMX;       // 2048
  const int grid = (n_tok + TOK_PER_BLK - 1) / TOK_PER_BLK;  // 256
  flfq_fused_kernel<<<grid, BLOCK, 0, stream>>>(x, Win, bin, Wout, bout, out, n_tok);
}